// Round 10
// baseline (1080.331 us; speedup 1.0000x reference)
//
#include <hip/hip_runtime.h>
#include <hip/hip_bf16.h>

typedef __attribute__((ext_vector_type(8))) short bf16x8;
typedef __attribute__((ext_vector_type(4))) float f32x4;

#define SBAR() __builtin_amdgcn_sched_barrier(0)
#define WBAR() __builtin_amdgcn_s_barrier()

template<int N> __device__ __forceinline__ void vmcw() {
  if constexpr (N == 4)      asm volatile("s_waitcnt vmcnt(4)" ::: "memory");
  else                       asm volatile("s_waitcnt vmcnt(0)" ::: "memory");
}

__device__ __forceinline__ ushort f2bf(float f) {
  union { float f; unsigned u; } v; v.f = f;
  unsigned r = v.u + 0x7fffu + ((v.u >> 16) & 1u);
  return (ushort)(r >> 16);
}

__device__ __forceinline__ void gld_lds16(const ushort* gsrc, ushort* lds) {
  __builtin_amdgcn_global_load_lds((const __attribute__((address_space(1))) void*)gsrc,
                                   (__attribute__((address_space(3))) void*)lds, 16, 0, 0);
}

__device__ __forceinline__ f32x4 MF(bf16x8 a, bf16x8 b, f32x4 c) {
  return __builtin_amdgcn_mfma_f32_16x16x32_bf16(a, b, c, 0, 0, 0);
}

__device__ __forceinline__ void xcd_map(int bid, int CT, int& r, int& c) {
  const int xcd = bid & 7, j = bid >> 3;
  r = xcd + 8 * (j / CT);
  c = j % CT;
}

__device__ __forceinline__ int expert_of(const int* g, int E, int m0) {
  int e = 0, base = 0;
  while (e < E - 1 && m0 >= base + g[e]) { base += g[e]; ++e; }
  return e;
}

// ================= pack x: [T][D] fp32 -> tiled-A bf16 (RB=256, BK=64, kc-major)
__global__ __launch_bounds__(256) void k_pack_x(
    const float* __restrict__ x, ushort* __restrict__ xb, int D) {
  __shared__ ushort sm[256][66];
  const int kt = blockIdx.x;
  const int rt = blockIdx.y;
  const int t = threadIdx.x;
  const int c0 = kt * 64;
  const size_t r0 = (size_t)rt * 256;
#pragma unroll
  for (int p = 0; p < 16; ++p) {
    const int row = p * 16 + (t >> 4);
    const float4 v = *reinterpret_cast<const float4*>(x + (r0 + row) * D + c0 + (t & 15) * 4);
    ushort4 u; u.x = f2bf(v.x); u.y = f2bf(v.y); u.z = f2bf(v.z); u.w = f2bf(v.w);
    *reinterpret_cast<ushort4*>(&sm[row][(t & 15) * 4]) = u;
  }
  __syncthreads();
  ushort* outp = xb + ((size_t)rt * (D >> 6) + kt) * 16384;
#pragma unroll
  for (int p = 0; p < 8; ++p) {
    ushort u[8];
#pragma unroll
    for (int j = 0; j < 8; ++j) u[j] = sm[t][p * 8 + j];
    *reinterpret_cast<uint4*>(outp + p * 2048 + t * 8) = *reinterpret_cast<uint4*>(u);
  }
}

// ================= pack w1+w3: [E][D][I] fp32 -> tiled-B^T bf16 (RB=128) ======
__global__ __launch_bounds__(256) void k_pack_w13(
    const float* __restrict__ w1, const float* __restrict__ w3,
    ushort* __restrict__ w1p, ushort* __restrict__ w3p, int R, int C) {
  __shared__ ushort sm[64][66];
  const int bz = blockIdx.z;
  const int e = bz >> 1;
  const size_t mat = (size_t)R * C;
  const float* s = ((bz & 1) ? w3 : w1) + (size_t)e * mat;
  ushort* d = ((bz & 1) ? w3p : w1p) + (size_t)e * mat;
  const int c0 = blockIdx.x * 64;  // n
  const int r0 = blockIdx.y * 64;  // k
  const int t = threadIdx.x;
#pragma unroll
  for (int p = 0; p < 4; ++p) {
    const int r = p * 16 + (t >> 4);
    const float4 v = *reinterpret_cast<const float4*>(s + (size_t)(r0 + r) * C + c0 + (t & 15) * 4);
    ushort4 u; u.x = f2bf(v.x); u.y = f2bf(v.y); u.z = f2bf(v.z); u.w = f2bf(v.w);
    *reinterpret_cast<ushort4*>(&sm[r][(t & 15) * 4]) = u;
  }
  __syncthreads();
  const size_t tilebase = ((size_t)(c0 >> 7) * (R >> 6) + (r0 >> 6)) * 8192;
  const int nbase = c0 & 127;
#pragma unroll
  for (int p = 0; p < 2; ++p) {
    const int uu = p * 256 + t;
    const int kc = uu >> 6;
    const int rr = uu & 63;
    ushort u[8];
#pragma unroll
    for (int j = 0; j < 8; ++j) u[j] = sm[kc * 8 + j][rr];
    *reinterpret_cast<uint4*>(d + tilebase + (size_t)kc * 1024 + (size_t)(nbase + rr) * 8) =
        *reinterpret_cast<uint4*>(u);
  }
}

// ================= pack w2: [E][I][D] fp32 -> tiled-B^T bf16 (RB=256) ======
__global__ __launch_bounds__(256) void k_pack_w2(
    const float* __restrict__ w, ushort* __restrict__ wp, int R, int C) {
  __shared__ ushort sm[64][66];
  const int e = blockIdx.z;
  const size_t mat = (size_t)R * C;
  const float* s = w + (size_t)e * mat;
  ushort* d = wp + (size_t)e * mat;
  const int c0 = blockIdx.x * 64;  // n
  const int r0 = blockIdx.y * 64;  // k
  const int t = threadIdx.x;
#pragma unroll
  for (int p = 0; p < 4; ++p) {
    const int r = p * 16 + (t >> 4);
    const float4 v = *reinterpret_cast<const float4*>(s + (size_t)(r0 + r) * C + c0 + (t & 15) * 4);
    ushort4 u; u.x = f2bf(v.x); u.y = f2bf(v.y); u.z = f2bf(v.z); u.w = f2bf(v.w);
    *reinterpret_cast<ushort4*>(&sm[r][(t & 15) * 4]) = u;
  }
  __syncthreads();
  const size_t tilebase = ((size_t)(c0 >> 8) * (R >> 6) + (r0 >> 6)) * 16384;
  const int nbase = c0 & 255;
#pragma unroll
  for (int p = 0; p < 2; ++p) {
    const int uu = p * 256 + t;
    const int kc = uu >> 6;
    const int rr = uu & 63;
    ushort u[8];
#pragma unroll
    for (int j = 0; j < 8; ++j) u[j] = sm[kc * 8 + j][rr];
    *reinterpret_cast<uint4*>(d + tilebase + (size_t)kc * 2048 + (size_t)(nbase + rr) * 8) =
        *reinterpret_cast<uint4*>(u);
  }
}

// ================= GEMM1 K-tile (BK=32): free-flow + wave anti-phase stagger =========
// buffer (16384 u): A[0,8192) kc-major(4 x 2048) ; B1[8192,12288) ; B3[12288,16384)
// half = wr (wave>>2): co-resident SIMD pairs have opposite half -> read/MFMA overlap
template<bool PF, int C>
__device__ __forceinline__ void g1_tile32(
    const ushort* cur, ushort* stg,
    const ushort* sA, const ushort* sB1, const ushort* sB3,
    int sto, int aoff, int b1off, int b3off, int half,
    f32x4 (&acc1)[8][2], f32x4 (&acc3)[8][2]) {
  SBAR();
  if (PF) {
    gld_lds16(sA + sto,        stg + sto);
    gld_lds16(sA + 4096 + sto, stg + 4096 + sto);
    gld_lds16(sB1 + sto,       stg + 8192 + sto);
    gld_lds16(sB3 + sto,       stg + 12288 + sto);
  }
  SBAR();
  bf16x8 af[4], b1f[2], b3f[2];
  b1f[0] = *(const bf16x8*)&cur[b1off];       b1f[1] = *(const bf16x8*)&cur[b1off + 128];
  b3f[0] = *(const bf16x8*)&cur[b3off];       b3f[1] = *(const bf16x8*)&cur[b3off + 128];
  if (half == 0) {
    // m-half 0 first
#pragma unroll
    for (int mi = 0; mi < 4; ++mi) af[mi] = *(const bf16x8*)&cur[aoff + mi * 128];
    __builtin_amdgcn_s_setprio(1);
#pragma unroll
    for (int mi = 0; mi < 4; ++mi)
#pragma unroll
      for (int ni = 0; ni < 2; ++ni) {
        acc1[mi][ni] = MF(af[mi], b1f[ni], acc1[mi][ni]);
        acc3[mi][ni] = MF(af[mi], b3f[ni], acc3[mi][ni]);
      }
    __builtin_amdgcn_s_setprio(0);
#pragma unroll
    for (int mi = 0; mi < 4; ++mi) af[mi] = *(const bf16x8*)&cur[aoff + (mi + 4) * 128];
    __builtin_amdgcn_s_setprio(1);
#pragma unroll
    for (int mi = 0; mi < 4; ++mi)
#pragma unroll
      for (int ni = 0; ni < 2; ++ni) {
        acc1[mi + 4][ni] = MF(af[mi], b1f[ni], acc1[mi + 4][ni]);
        acc3[mi + 4][ni] = MF(af[mi], b3f[ni], acc3[mi + 4][ni]);
      }
    __builtin_amdgcn_s_setprio(0);
  } else {
    // m-half 1 first (anti-phase)
#pragma unroll
    for (int mi = 0; mi < 4; ++mi) af[mi] = *(const bf16x8*)&cur[aoff + (mi + 4) * 128];
    __builtin_amdgcn_s_setprio(1);
#pragma unroll
    for (int mi = 0; mi < 4; ++mi)
#pragma unroll
      for (int ni = 0; ni < 2; ++ni) {
        acc1[mi + 4][ni] = MF(af[mi], b1f[ni], acc1[mi + 4][ni]);
        acc3[mi + 4][ni] = MF(af[mi], b3f[ni], acc3[mi + 4][ni]);
      }
    __builtin_amdgcn_s_setprio(0);
#pragma unroll
    for (int mi = 0; mi < 4; ++mi) af[mi] = *(const bf16x8*)&cur[aoff + mi * 128];
    __builtin_amdgcn_s_setprio(1);
#pragma unroll
    for (int mi = 0; mi < 4; ++mi)
#pragma unroll
      for (int ni = 0; ni < 2; ++ni) {
        acc1[mi][ni] = MF(af[mi], b1f[ni], acc1[mi][ni]);
        acc3[mi][ni] = MF(af[mi], b3f[ni], acc3[mi][ni]);
      }
    __builtin_amdgcn_s_setprio(0);
  }
  vmcw<C>();
  WBAR();
}

// ================= GEMM1: h = silu(x@w1)*(x@w3), 256x(128+128), BK=32 =================
__global__ __launch_bounds__(512, 2) void k_gemm1_8p(
    const ushort* __restrict__ xb, const ushort* __restrict__ w1p,
    const ushort* __restrict__ w3p, const int* __restrict__ g,
    ushort* __restrict__ h, int T, int D, int I, int E) {
  __shared__ ushort lds[3 * 16384];  // 96 KiB, 3 rotating buffers

  const int CT = I >> 7;
  int r, c; xcd_map(blockIdx.x, CT, r, c);
  const int m0 = r << 8, n0 = c << 7;
  const int e = expert_of(g, E, m0);

  const int tid = threadIdx.x;
  const int lane = tid & 63, wave = tid >> 6;
  const int wr = wave >> 2, wc = wave & 3;
  const int l15 = lane & 15, l16 = lane >> 4;

  const int KT = D >> 5;  // 128 tiles of k=32
  const ushort* pA  = xb  + (size_t)r * (D >> 6) * 16384;   // half-tiles linear @8192
  const ushort* pB1 = w1p + (size_t)e * I * D + (size_t)c * (D >> 6) * 8192;  // @4096
  const ushort* pB3 = w3p + (size_t)e * I * D + (size_t)c * (D >> 6) * 8192;

  const int sto = tid * 8;                         // [0,4096)
  const int aoff  = l16 * 2048 + (wr * 128 + l15) * 8;
  const int b1off = 8192 + l16 * 1024 + (wc * 32 + l15) * 8;
  const int b3off = b1off + 4096;

  const f32x4 zero = {0.f, 0.f, 0.f, 0.f};
  f32x4 acc1[8][2], acc3[8][2];
#pragma unroll
  for (int mi = 0; mi < 8; ++mi)
#pragma unroll
    for (int ni = 0; ni < 2; ++ni) { acc1[mi][ni] = zero; acc3[mi][ni] = zero; }

  // prologue: stage tiles 0,1 into bufs 0,1
  {
    ushort* L0 = lds; ushort* L1 = lds + 16384;
    gld_lds16(pA + sto,          L0 + sto);
    gld_lds16(pA + 4096 + sto,   L0 + 4096 + sto);
    gld_lds16(pB1 + sto,         L0 + 8192 + sto);
    gld_lds16(pB3 + sto,         L0 + 12288 + sto);
    gld_lds16(pA + 8192 + sto,   L1 + sto);
    gld_lds16(pA + 12288 + sto,  L1 + 4096 + sto);
    gld_lds16(pB1 + 4096 + sto,  L1 + 8192 + sto);
    gld_lds16(pB3 + 4096 + sto,  L1 + 12288 + sto);
  }
  vmcw<4>(); WBAR();

  const ushort* sA  = pA  + 2 * 8192;
  const ushort* sB1 = pB1 + 2 * 4096;
  const ushort* sB3 = pB3 + 2 * 4096;
  int curo = 0, stgo = 2 * 16384;

  for (int t = 0; t < KT - 2; ++t) {
    g1_tile32<true, 4>(lds + curo, lds + stgo, sA, sB1, sB3,
                       sto, aoff, b1off, b3off, wr, acc1, acc3);
    sA += 8192; sB1 += 4096; sB3 += 4096;
    curo = (curo == 32768) ? 0 : curo + 16384;
    stgo = (stgo == 32768) ? 0 : stgo + 16384;
  }
  g1_tile32<false, 0>(lds + curo, lds, sA, sB1, sB3, sto, aoff, b1off, b3off, wr, acc1, acc3);
  curo = (curo == 32768) ? 0 : curo + 16384;
  g1_tile32<false, 0>(lds + curo, lds, sA, sB1, sB3, sto, aoff, b1off, b3off, wr, acc1, acc3);

  // epilogue: SwiGLU -> h in tiled-A layout (RB=256, K=I)
#pragma unroll
  for (int mi = 0; mi < 8; ++mi)
#pragma unroll
    for (int ni = 0; ni < 2; ++ni)
#pragma unroll
      for (int rr = 0; rr < 4; ++rr) {
        const float v1 = acc1[mi][ni][rr];
        const float v3 = acc3[mi][ni][rr];
        const float sv = v1 / (1.f + __expf(-v1));
        const int row = m0 + wr * 128 + mi * 16 + l16 * 4 + rr;
        const int col = n0 + wc * 32 + ni * 16 + l15;
        const size_t off = ((size_t)(row >> 8) * (I >> 6) + (col >> 6)) * 16384 +
                           ((col >> 3) & 7) * 2048 + (row & 255) * 8 + (col & 7);
        h[off] = f2bf(sv * v3);
      }
}

// ================= GEMM2 K-tile (BK=32): free-flow + wave anti-phase stagger =========
// buffer: A[0,8192) kc-major(4 x 2048) ; B[8192,16384) kc-major(4 x 2048)
template<bool PF, int C>
__device__ __forceinline__ void g2_tile32(
    const ushort* cur, ushort* stg,
    const ushort* sA, const ushort* sB,
    int sto, int aoff, int boff, int half, f32x4 (&acc)[8][4]) {
  SBAR();
  if (PF) {
    gld_lds16(sA + sto,        stg + sto);
    gld_lds16(sA + 4096 + sto, stg + 4096 + sto);
    gld_lds16(sB + sto,        stg + 8192 + sto);
    gld_lds16(sB + 4096 + sto, stg + 12288 + sto);
  }
  SBAR();
  bf16x8 af[4], bf[4];
#pragma unroll
  for (int ni = 0; ni < 4; ++ni) bf[ni] = *(const bf16x8*)&cur[boff + ni * 128];
  if (half == 0) {
#pragma unroll
    for (int mi = 0; mi < 4; ++mi) af[mi] = *(const bf16x8*)&cur[aoff + mi * 128];
    __builtin_amdgcn_s_setprio(1);
#pragma unroll
    for (int mi = 0; mi < 4; ++mi)
#pragma unroll
      for (int ni = 0; ni < 4; ++ni) acc[mi][ni] = MF(af[mi], bf[ni], acc[mi][ni]);
    __builtin_amdgcn_s_setprio(0);
#pragma unroll
    for (int mi = 0; mi < 4; ++mi) af[mi] = *(const bf16x8*)&cur[aoff + (mi + 4) * 128];
    __builtin_amdgcn_s_setprio(1);
#pragma unroll
    for (int mi = 0; mi < 4; ++mi)
#pragma unroll
      for (int ni = 0; ni < 4; ++ni) acc[mi + 4][ni] = MF(af[mi], bf[ni], acc[mi + 4][ni]);
    __builtin_amdgcn_s_setprio(0);
  } else {
#pragma unroll
    for (int mi = 0; mi < 4; ++mi) af[mi] = *(const bf16x8*)&cur[aoff + (mi + 4) * 128];
    __builtin_amdgcn_s_setprio(1);
#pragma unroll
    for (int mi = 0; mi < 4; ++mi)
#pragma unroll
      for (int ni = 0; ni < 4; ++ni) acc[mi + 4][ni] = MF(af[mi], bf[ni], acc[mi + 4][ni]);
    __builtin_amdgcn_s_setprio(0);
#pragma unroll
    for (int mi = 0; mi < 4; ++mi) af[mi] = *(const bf16x8*)&cur[aoff + mi * 128];
    __builtin_amdgcn_s_setprio(1);
#pragma unroll
    for (int mi = 0; mi < 4; ++mi)
#pragma unroll
      for (int ni = 0; ni < 4; ++ni) acc[mi][ni] = MF(af[mi], bf[ni], acc[mi][ni]);
    __builtin_amdgcn_s_setprio(0);
  }
  vmcw<C>();
  WBAR();
}

// ================= GEMM2: out = h @ w2, 256x256, BK=32, fp32 out =================
__global__ __launch_bounds__(512, 2) void k_gemm2_8p(
    const ushort* __restrict__ h, const ushort* __restrict__ w2p,
    const int* __restrict__ g, float* __restrict__ out,
    int T, int D, int I, int E) {
  __shared__ ushort lds[3 * 16384];

  const int CT = D >> 8;
  int r, cb; xcd_map(blockIdx.x, CT, r, cb);
  const int m0 = r << 8, n0 = cb << 8;
  const int e = expert_of(g, E, m0);

  const int tid = threadIdx.x;
  const int lane = tid & 63, wave = tid >> 6;
  const int wr = wave >> 2, wc = wave & 3;
  const int l15 = lane & 15, l16 = lane >> 4;

  const int KT = I >> 5;  // 32 tiles
  const ushort* pA = h   + (size_t)r * (I >> 6) * 16384;                       // @8192
  const ushort* pB = w2p + (size_t)e * D * I + (size_t)cb * (I >> 6) * 16384;  // @8192

  const int sto = tid * 8;
  const int aoff = l16 * 2048 + (wr * 128 + l15) * 8;
  const int boff = 8192 + l16 * 2048 + (wc * 64 + l15) * 8;

  const f32x4 zero = {0.f, 0.f, 0.f, 0.f};
  f32x4 acc[8][4];
#pragma unroll
  for (int mi = 0; mi < 8; ++mi)
#pragma unroll
    for (int ni = 0; ni < 4; ++ni) acc[mi][ni] = zero;

  {
    ushort* L0 = lds; ushort* L1 = lds + 16384;
    gld_lds16(pA + sto,          L0 + sto);
    gld_lds16(pA + 4096 + sto,   L0 + 4096 + sto);
    gld_lds16(pB + sto,          L0 + 8192 + sto);
    gld_lds16(pB + 4096 + sto,   L0 + 12288 + sto);
    gld_lds16(pA + 8192 + sto,   L1 + sto);
    gld_lds16(pA + 12288 + sto,  L1 + 4096 + sto);
    gld_lds16(pB + 8192 + sto,   L1 + 8192 + sto);
    gld_lds16(pB + 12288 + sto,  L1 + 12288 + sto);
  }
  vmcw<4>(); WBAR();

  const ushort* sA = pA + 2 * 8192;
  const ushort* sB = pB + 2 * 8192;
  int curo = 0, stgo = 2 * 16384;

  for (int t = 0; t < KT - 2; ++t) {
    g2_tile32<true, 4>(lds + curo, lds + stgo, sA, sB, sto, aoff, boff, wr, acc);
    sA += 8192; sB += 8192;
    curo = (curo == 32768) ? 0 : curo + 16384;
    stgo = (stgo == 32768) ? 0 : stgo + 16384;
  }
  g2_tile32<false, 0>(lds + curo, lds, sA, sB, sto, aoff, boff, wr, acc);
  curo = (curo == 32768) ? 0 : curo + 16384;
  g2_tile32<false, 0>(lds + curo, lds, sA, sB, sto, aoff, boff, wr, acc);

#pragma unroll
  for (int mi = 0; mi < 8; ++mi)
#pragma unroll
    for (int ni = 0; ni < 4; ++ni)
#pragma unroll
      for (int rr = 0; rr < 4; ++rr) {
        const int row = m0 + wr * 128 + mi * 16 + l16 * 4 + rr;
        const int col = n0 + wc * 64 + ni * 16 + l15;
        out[(size_t)row * D + col] = acc[mi][ni][rr];
      }
}

// ================= launch =================
extern "C" void kernel_launch(void* const* d_in, const int* in_sizes, int n_in,
                              void* d_out, int out_size, void* d_ws, size_t ws_size,
                              hipStream_t stream) {
  const float* x  = (const float*)d_in[0];
  const float* w1 = (const float*)d_in[1];
  const float* w2 = (const float*)d_in[2];
  const float* w3 = (const float*)d_in[3];
  const int*   g  = (const int*)d_in[4];

  const int E = in_sizes[4];
  const int D = 4096;
  const int I = 1024;
  const int T = in_sizes[0] / D;

  const size_t szW = (size_t)E * D * I * sizeof(ushort);  // 64 MB
  const size_t szH = (size_t)T * I * sizeof(ushort);      // 64 MB
  const size_t szX = (size_t)T * D * sizeof(ushort);      // 256 MB
  const size_t need = 2 * szW + szH + szX;                // 448 MB (proven available)
  if (ws_size < need) return;

  char* ws = (char*)d_ws;
  ushort* w1p = (ushort*)ws;              // slot 0 (reused by w2p after gemm1)
  ushort* w3p = (ushort*)(ws + szW);      // slot 1
  ushort* h   = (ushort*)(ws + 2 * szW);  // slot 2
  ushort* xb  = (ushort*)(ws + 2 * szW + szH);
  ushort* w2p = w1p;

  float* out = (float*)d_out;

  k_pack_w13<<<dim3(I / 64, D / 64, 2 * E), 256, 0, stream>>>(w1, w3, w1p, w3p, D, I);
  k_pack_x<<<dim3(D / 64, T / 256), 256, 0, stream>>>(x, xb, D);

  k_gemm1_8p<<<dim3((T / 256) * (I / 128)), 512, 0, stream>>>(xb, w1p, w3p, g, h, T, D, I, E);

  k_pack_w2<<<dim3(D / 64, I / 64, E), 256, 0, stream>>>(w2, w2p, I, D);

  k_gemm2_8p<<<dim3((T / 256) * (D / 256)), 512, 0, stream>>>(h, w2p, g, out, T, D, I, E);
}

// Round 11
// 1044.707 us; speedup vs baseline: 1.0341x; 1.0341x over previous
//
#include <hip/hip_runtime.h>
#include <hip/hip_bf16.h>

typedef __attribute__((ext_vector_type(8))) short bf16x8;
typedef __attribute__((ext_vector_type(4))) float f32x4;

#define SBAR() __builtin_amdgcn_sched_barrier(0)
#define WBAR() __builtin_amdgcn_s_barrier()

template<int N> __device__ __forceinline__ void vmcw() {
  if constexpr (N == 4)      asm volatile("s_waitcnt vmcnt(4)" ::: "memory");
  else                       asm volatile("s_waitcnt vmcnt(0)" ::: "memory");
}

__device__ __forceinline__ ushort f2bf(float f) {
  union { float f; unsigned u; } v; v.f = f;
  unsigned r = v.u + 0x7fffu + ((v.u >> 16) & 1u);
  return (ushort)(r >> 16);
}

__device__ __forceinline__ void gld_lds16(const ushort* gsrc, ushort* lds) {
  __builtin_amdgcn_global_load_lds((const __attribute__((address_space(1))) void*)gsrc,
                                   (__attribute__((address_space(3))) void*)lds, 16, 0, 0);
}

__device__ __forceinline__ f32x4 MF(bf16x8 a, bf16x8 b, f32x4 c) {
  return __builtin_amdgcn_mfma_f32_16x16x32_bf16(a, b, c, 0, 0, 0);
}

__device__ __forceinline__ void xcd_map(int bid, int CT, int& r, int& c) {
  const int xcd = bid & 7, j = bid >> 3;
  r = xcd + 8 * (j / CT);
  c = j % CT;
}

__device__ __forceinline__ int expert_of(const int* g, int E, int m0) {
  int e = 0, base = 0;
  while (e < E - 1 && m0 >= base + g[e]) { base += g[e]; ++e; }
  return e;
}

// ================= pack x: [T][D] fp32 -> tiled-A bf16 (RB=256, BK=64, kc-major)
// tile(rt,kt) base = (rt*(D/64)+kt)*16384 ; within: kc*2048 + row*8 + j
// NOTE: along k (fixed rt) this layout is LINEAR: 32-k half-tiles at stride 8192.
__global__ __launch_bounds__(256) void k_pack_x(
    const float* __restrict__ x, ushort* __restrict__ xb, int D) {
  __shared__ ushort sm[256][66];
  const int kt = blockIdx.x;
  const int rt = blockIdx.y;
  const int t = threadIdx.x;
  const int c0 = kt * 64;
  const size_t r0 = (size_t)rt * 256;
#pragma unroll
  for (int p = 0; p < 16; ++p) {
    const int row = p * 16 + (t >> 4);
    const float4 v = *reinterpret_cast<const float4*>(x + (r0 + row) * D + c0 + (t & 15) * 4);
    ushort4 u; u.x = f2bf(v.x); u.y = f2bf(v.y); u.z = f2bf(v.z); u.w = f2bf(v.w);
    *reinterpret_cast<ushort4*>(&sm[row][(t & 15) * 4]) = u;
  }
  __syncthreads();
  ushort* outp = xb + ((size_t)rt * (D >> 6) + kt) * 16384;
#pragma unroll
  for (int p = 0; p < 8; ++p) {
    ushort u[8];
#pragma unroll
    for (int j = 0; j < 8; ++j) u[j] = sm[t][p * 8 + j];
    *reinterpret_cast<uint4*>(outp + p * 2048 + t * 8) = *reinterpret_cast<uint4*>(u);
  }
}

// ================= pack w1+w3: [E][D][I] fp32 -> tiled-B^T bf16 (RB=128) ======
__global__ __launch_bounds__(256) void k_pack_w13(
    const float* __restrict__ w1, const float* __restrict__ w3,
    ushort* __restrict__ w1p, ushort* __restrict__ w3p, int R, int C) {
  __shared__ ushort sm[64][66];
  const int bz = blockIdx.z;
  const int e = bz >> 1;
  const size_t mat = (size_t)R * C;
  const float* s = ((bz & 1) ? w3 : w1) + (size_t)e * mat;
  ushort* d = ((bz & 1) ? w3p : w1p) + (size_t)e * mat;
  const int c0 = blockIdx.x * 64;  // n
  const int r0 = blockIdx.y * 64;  // k
  const int t = threadIdx.x;
#pragma unroll
  for (int p = 0; p < 4; ++p) {
    const int r = p * 16 + (t >> 4);
    const float4 v = *reinterpret_cast<const float4*>(s + (size_t)(r0 + r) * C + c0 + (t & 15) * 4);
    ushort4 u; u.x = f2bf(v.x); u.y = f2bf(v.y); u.z = f2bf(v.z); u.w = f2bf(v.w);
    *reinterpret_cast<ushort4*>(&sm[r][(t & 15) * 4]) = u;
  }
  __syncthreads();
  const size_t tilebase = ((size_t)(c0 >> 7) * (R >> 6) + (r0 >> 6)) * 8192;
  const int nbase = c0 & 127;
#pragma unroll
  for (int p = 0; p < 2; ++p) {
    const int uu = p * 256 + t;
    const int kc = uu >> 6;
    const int rr = uu & 63;
    ushort u[8];
#pragma unroll
    for (int j = 0; j < 8; ++j) u[j] = sm[kc * 8 + j][rr];
    *reinterpret_cast<uint4*>(d + tilebase + (size_t)kc * 1024 + (size_t)(nbase + rr) * 8) =
        *reinterpret_cast<uint4*>(u);
  }
}

// ================= pack w2: [E][I][D] fp32 -> tiled-B^T bf16 (RB=256) ======
__global__ __launch_bounds__(256) void k_pack_w2(
    const float* __restrict__ w, ushort* __restrict__ wp, int R, int C) {
  __shared__ ushort sm[64][66];
  const int e = blockIdx.z;
  const size_t mat = (size_t)R * C;
  const float* s = w + (size_t)e * mat;
  ushort* d = wp + (size_t)e * mat;
  const int c0 = blockIdx.x * 64;  // n
  const int r0 = blockIdx.y * 64;  // k
  const int t = threadIdx.x;
#pragma unroll
  for (int p = 0; p < 4; ++p) {
    const int r = p * 16 + (t >> 4);
    const float4 v = *reinterpret_cast<const float4*>(s + (size_t)(r0 + r) * C + c0 + (t & 15) * 4);
    ushort4 u; u.x = f2bf(v.x); u.y = f2bf(v.y); u.z = f2bf(v.z); u.w = f2bf(v.w);
    *reinterpret_cast<ushort4*>(&sm[r][(t & 15) * 4]) = u;
  }
  __syncthreads();
  const size_t tilebase = ((size_t)(c0 >> 8) * (R >> 6) + (r0 >> 6)) * 16384;
  const int nbase = c0 & 255;
#pragma unroll
  for (int p = 0; p < 2; ++p) {
    const int uu = p * 256 + t;
    const int kc = uu >> 6;
    const int rr = uu & 63;
    ushort u[8];
#pragma unroll
    for (int j = 0; j < 8; ++j) u[j] = sm[kc * 8 + j][rr];
    *reinterpret_cast<uint4*>(d + tilebase + (size_t)kc * 2048 + (size_t)(nbase + rr) * 8) =
        *reinterpret_cast<uint4*>(u);
  }
}

// ================= GEMM1 K-tile (BK=32): free-flow, 1 barrier/tile, 3 buffers ========
// buffer (16384 u): A[0,8192) kc-major(4 x 2048) ; B1[8192,12288) ; B3[12288,16384)
template<bool PF, int C>
__device__ __forceinline__ void g1_tile32(
    const ushort* cur, ushort* stg,
    const ushort* sA, const ushort* sB1, const ushort* sB3,
    int sto, int aoff, int b1off, int b3off,
    f32x4 (&acc1)[8][2], f32x4 (&acc3)[8][2]) {
  SBAR();   // pin: nothing crosses from before the tile-start barrier
  if (PF) { // refill buf[(t+2)%3] — read by all waves in tile t-1, WAR-safe now
    gld_lds16(sA + sto,        stg + sto);
    gld_lds16(sA + 4096 + sto, stg + 4096 + sto);
    gld_lds16(sB1 + sto,       stg + 8192 + sto);
    gld_lds16(sB3 + sto,       stg + 12288 + sto);
  }
  SBAR();   // loads issued early; reads/MFMA free-flow below
  bf16x8 af[8], b1f[2], b3f[2];
#pragma unroll
  for (int mi = 0; mi < 8; ++mi) af[mi] = *(const bf16x8*)&cur[aoff + mi * 128];
  b1f[0] = *(const bf16x8*)&cur[b1off];       b1f[1] = *(const bf16x8*)&cur[b1off + 128];
  b3f[0] = *(const bf16x8*)&cur[b3off];       b3f[1] = *(const bf16x8*)&cur[b3off + 128];
  __builtin_amdgcn_s_setprio(1);
#pragma unroll
  for (int mi = 0; mi < 8; ++mi)
#pragma unroll
    for (int ni = 0; ni < 2; ++ni) {
      acc1[mi][ni] = MF(af[mi], b1f[ni], acc1[mi][ni]);
      acc3[mi][ni] = MF(af[mi], b3f[ni], acc3[mi][ni]);
    }
  __builtin_amdgcn_s_setprio(0);
  vmcw<C>();   // steady: keep t+2's 4 loads in flight; gate t+1's
  WBAR();      // single tile barrier
}

// ================= GEMM1: h = silu(x@w1)*(x@w3), 256x(128+128), BK=32 =================
__global__ __launch_bounds__(512, 2) void k_gemm1_8p(
    const ushort* __restrict__ xb, const ushort* __restrict__ w1p,
    const ushort* __restrict__ w3p, const int* __restrict__ g,
    ushort* __restrict__ h, int T, int D, int I, int E) {
  __shared__ ushort lds[3 * 16384];  // 96 KiB, 3 rotating buffers

  const int CT = I >> 7;
  int r, c; xcd_map(blockIdx.x, CT, r, c);
  const int m0 = r << 8, n0 = c << 7;
  const int e = expert_of(g, E, m0);

  const int tid = threadIdx.x;
  const int lane = tid & 63, wave = tid >> 6;
  const int wr = wave >> 2, wc = wave & 3;
  const int l15 = lane & 15, l16 = lane >> 4;

  const int KT = D >> 5;  // 128 tiles of k=32
  const ushort* pA  = xb  + (size_t)r * (D >> 6) * 16384;   // half-tiles linear @8192
  const ushort* pB1 = w1p + (size_t)e * I * D + (size_t)c * (D >> 6) * 8192;  // @4096
  const ushort* pB3 = w3p + (size_t)e * I * D + (size_t)c * (D >> 6) * 8192;

  const int sto = tid * 8;                         // [0,4096)
  const int aoff  = l16 * 2048 + (wr * 128 + l15) * 8;
  const int b1off = 8192 + l16 * 1024 + (wc * 32 + l15) * 8;
  const int b3off = b1off + 4096;

  const f32x4 zero = {0.f, 0.f, 0.f, 0.f};
  f32x4 acc1[8][2], acc3[8][2];
#pragma unroll
  for (int mi = 0; mi < 8; ++mi)
#pragma unroll
    for (int ni = 0; ni < 2; ++ni) { acc1[mi][ni] = zero; acc3[mi][ni] = zero; }

  // prologue: stage tiles 0,1 into bufs 0,1
  {
    ushort* L0 = lds; ushort* L1 = lds + 16384;
    gld_lds16(pA + sto,          L0 + sto);
    gld_lds16(pA + 4096 + sto,   L0 + 4096 + sto);
    gld_lds16(pB1 + sto,         L0 + 8192 + sto);
    gld_lds16(pB3 + sto,         L0 + 12288 + sto);
    gld_lds16(pA + 8192 + sto,   L1 + sto);
    gld_lds16(pA + 12288 + sto,  L1 + 4096 + sto);
    gld_lds16(pB1 + 4096 + sto,  L1 + 8192 + sto);
    gld_lds16(pB3 + 4096 + sto,  L1 + 12288 + sto);
  }
  vmcw<4>(); WBAR();

  const ushort* sA  = pA  + 2 * 8192;
  const ushort* sB1 = pB1 + 2 * 4096;
  const ushort* sB3 = pB3 + 2 * 4096;
  int curo = 0, stgo = 2 * 16384;

  for (int t = 0; t < KT - 2; ++t) {
    g1_tile32<true, 4>(lds + curo, lds + stgo, sA, sB1, sB3,
                       sto, aoff, b1off, b3off, acc1, acc3);
    sA += 8192; sB1 += 4096; sB3 += 4096;
    curo = (curo == 32768) ? 0 : curo + 16384;
    stgo = (stgo == 32768) ? 0 : stgo + 16384;
  }
  g1_tile32<false, 0>(lds + curo, lds, sA, sB1, sB3, sto, aoff, b1off, b3off, acc1, acc3);
  curo = (curo == 32768) ? 0 : curo + 16384;
  g1_tile32<false, 0>(lds + curo, lds, sA, sB1, sB3, sto, aoff, b1off, b3off, acc1, acc3);

  // epilogue: SwiGLU -> h in tiled-A layout (RB=256, K=I)
#pragma unroll
  for (int mi = 0; mi < 8; ++mi)
#pragma unroll
    for (int ni = 0; ni < 2; ++ni)
#pragma unroll
      for (int rr = 0; rr < 4; ++rr) {
        const float v1 = acc1[mi][ni][rr];
        const float v3 = acc3[mi][ni][rr];
        const float sv = v1 / (1.f + __expf(-v1));
        const int row = m0 + wr * 128 + mi * 16 + l16 * 4 + rr;
        const int col = n0 + wc * 32 + ni * 16 + l15;
        const size_t off = ((size_t)(row >> 8) * (I >> 6) + (col >> 6)) * 16384 +
                           ((col >> 3) & 7) * 2048 + (row & 255) * 8 + (col & 7);
        h[off] = f2bf(sv * v3);
      }
}

// ================= GEMM2 K-tile (BK=32): free-flow, 1 barrier/tile, 3 buffers ========
// buffer: A[0,8192) kc-major(4 x 2048) ; B[8192,16384) kc-major(4 x 2048)
template<bool PF, int C>
__device__ __forceinline__ void g2_tile32(
    const ushort* cur, ushort* stg,
    const ushort* sA, const ushort* sB,
    int sto, int aoff, int boff, f32x4 (&acc)[8][4]) {
  SBAR();
  if (PF) {
    gld_lds16(sA + sto,        stg + sto);
    gld_lds16(sA + 4096 + sto, stg + 4096 + sto);
    gld_lds16(sB + sto,        stg + 8192 + sto);
    gld_lds16(sB + 4096 + sto, stg + 12288 + sto);
  }
  SBAR();
  bf16x8 af[8], bf[4];
#pragma unroll
  for (int mi = 0; mi < 8; ++mi) af[mi] = *(const bf16x8*)&cur[aoff + mi * 128];
#pragma unroll
  for (int ni = 0; ni < 4; ++ni) bf[ni] = *(const bf16x8*)&cur[boff + ni * 128];
  __builtin_amdgcn_s_setprio(1);
#pragma unroll
  for (int mi = 0; mi < 8; ++mi)
#pragma unroll
    for (int ni = 0; ni < 4; ++ni) acc[mi][ni] = MF(af[mi], bf[ni], acc[mi][ni]);
  __builtin_amdgcn_s_setprio(0);
  vmcw<C>();
  WBAR();
}

// ================= GEMM2: out = h @ w2, 256x256, BK=32, fp32 out =================
__global__ __launch_bounds__(512, 2) void k_gemm2_8p(
    const ushort* __restrict__ h, const ushort* __restrict__ w2p,
    const int* __restrict__ g, float* __restrict__ out,
    int T, int D, int I, int E) {
  __shared__ ushort lds[3 * 16384];

  const int CT = D >> 8;
  int r, cb; xcd_map(blockIdx.x, CT, r, cb);
  const int m0 = r << 8, n0 = cb << 8;
  const int e = expert_of(g, E, m0);

  const int tid = threadIdx.x;
  const int lane = tid & 63, wave = tid >> 6;
  const int wr = wave >> 2, wc = wave & 3;
  const int l15 = lane & 15, l16 = lane >> 4;

  const int KT = I >> 5;  // 32 tiles
  const ushort* pA = h   + (size_t)r * (I >> 6) * 16384;                       // @8192
  const ushort* pB = w2p + (size_t)e * D * I + (size_t)cb * (I >> 6) * 16384;  // @8192

  const int sto = tid * 8;
  const int aoff = l16 * 2048 + (wr * 128 + l15) * 8;
  const int boff = 8192 + l16 * 2048 + (wc * 64 + l15) * 8;

  const f32x4 zero = {0.f, 0.f, 0.f, 0.f};
  f32x4 acc[8][4];
#pragma unroll
  for (int mi = 0; mi < 8; ++mi)
#pragma unroll
    for (int ni = 0; ni < 4; ++ni) acc[mi][ni] = zero;

  {
    ushort* L0 = lds; ushort* L1 = lds + 16384;
    gld_lds16(pA + sto,          L0 + sto);
    gld_lds16(pA + 4096 + sto,   L0 + 4096 + sto);
    gld_lds16(pB + sto,          L0 + 8192 + sto);
    gld_lds16(pB + 4096 + sto,   L0 + 12288 + sto);
    gld_lds16(pA + 8192 + sto,   L1 + sto);
    gld_lds16(pA + 12288 + sto,  L1 + 4096 + sto);
    gld_lds16(pB + 8192 + sto,   L1 + 8192 + sto);
    gld_lds16(pB + 12288 + sto,  L1 + 12288 + sto);
  }
  vmcw<4>(); WBAR();

  const ushort* sA = pA + 2 * 8192;
  const ushort* sB = pB + 2 * 8192;
  int curo = 0, stgo = 2 * 16384;

  for (int t = 0; t < KT - 2; ++t) {
    g2_tile32<true, 4>(lds + curo, lds + stgo, sA, sB, sto, aoff, boff, acc);
    sA += 8192; sB += 8192;
    curo = (curo == 32768) ? 0 : curo + 16384;
    stgo = (stgo == 32768) ? 0 : stgo + 16384;
  }
  g2_tile32<false, 0>(lds + curo, lds, sA, sB, sto, aoff, boff, acc);
  curo = (curo == 32768) ? 0 : curo + 16384;
  g2_tile32<false, 0>(lds + curo, lds, sA, sB, sto, aoff, boff, acc);

#pragma unroll
  for (int mi = 0; mi < 8; ++mi)
#pragma unroll
    for (int ni = 0; ni < 4; ++ni)
#pragma unroll
      for (int rr = 0; rr < 4; ++rr) {
        const int row = m0 + wr * 128 + mi * 16 + l16 * 4 + rr;
        const int col = n0 + wc * 64 + ni * 16 + l15;
        out[(size_t)row * D + col] = acc[mi][ni][rr];
      }
}

// ================= launch =================
extern "C" void kernel_launch(void* const* d_in, const int* in_sizes, int n_in,
                              void* d_out, int out_size, void* d_ws, size_t ws_size,
                              hipStream_t stream) {
  const float* x  = (const float*)d_in[0];
  const float* w1 = (const float*)d_in[1];
  const float* w2 = (const float*)d_in[2];
  const float* w3 = (const float*)d_in[3];
  const int*   g  = (const int*)d_in[4];

  const int E = in_sizes[4];
  const int D = 4096;
  const int I = 1024;
  const int T = in_sizes[0] / D;

  const size_t szW = (size_t)E * D * I * sizeof(ushort);  // 64 MB
  const size_t szH = (size_t)T * I * sizeof(ushort);      // 64 MB
  const size_t szX = (size_t)T * D * sizeof(ushort);      // 256 MB
  const size_t need = 2 * szW + szH + szX;                // 448 MB (proven available)
  if (ws_size < need) return;

  char* ws = (char*)d_ws;
  ushort* w1p = (ushort*)ws;              // slot 0 (reused by w2p after gemm1)
  ushort* w3p = (ushort*)(ws + szW);      // slot 1
  ushort* h   = (ushort*)(ws + 2 * szW);  // slot 2
  ushort* xb  = (ushort*)(ws + 2 * szW + szH);
  ushort* w2p = w1p;

  float* out = (float*)d_out;

  k_pack_w13<<<dim3(I / 64, D / 64, 2 * E), 256, 0, stream>>>(w1, w3, w1p, w3p, D, I);
  k_pack_x<<<dim3(D / 64, T / 256), 256, 0, stream>>>(x, xb, D);

  k_gemm1_8p<<<dim3((T / 256) * (I / 128)), 512, 0, stream>>>(xb, w1p, w3p, g, h, T, D, I, E);

  k_pack_w2<<<dim3(D / 64, I / 64, E), 256, 0, stream>>>(w2, w2p, I, D);

  k_gemm2_8p<<<dim3((T / 256) * (D / 256)), 512, 0, stream>>>(h, w2p, g, out, T, D, I, E);
}